// Round 2
// baseline (1924.244 us; speedup 1.0000x reference)
//
#include <hip/hip_runtime.h>
#include <stdint.h>

#define TMASK ((1u << 19) - 1u)

struct F2 { float x, y; };
typedef float v4f __attribute__((ext_vector_type(4)));

__global__ __launch_bounds__(256)
void sdf_fused(const float* __restrict__ inp,
               const float* __restrict__ tables,
               const float* __restrict__ W1, const float* __restrict__ b1,
               const float* __restrict__ W2, const float* __restrict__ b2,
               const float* __restrict__ W3, const float* __restrict__ b3,
               float* __restrict__ out, int n)
{
    const int gid = blockIdx.x * blockDim.x + threadIdx.x;
    if (gid >= n) return;

    // Nontemporal input read (single-touch stream; keep tables cache-resident)
    const float i0 = __builtin_nontemporal_load(inp + 3 * (size_t)gid + 0);
    const float i1 = __builtin_nontemporal_load(inp + 3 * (size_t)gid + 1);
    const float i2 = __builtin_nontemporal_load(inp + 3 * (size_t)gid + 2);
    const float x0 = (i0 + 3.0f) / 6.0f;
    const float x1 = (i1 + 3.0f) / 6.0f;
    const float x2 = (i2 + 3.0f) / 6.0f;

    // scale_l = 16 * 1.3819^l - 1 (computed in double, rounded to f32)
    constexpr float SC[16] = {
        15.0f,            21.1104f,         29.55436176f,     41.22307252259f,
        57.34806391006f,  79.63118951731f,  110.42424079360f, 152.97715835200f,
        211.78103512800f, 293.04211244300f, 405.33679518600f, 560.51681726700f,
        774.96008978200f, 1071.29924807000f,1480.81033091000f,2046.71369628000f };
    constexpr uint32_t RES[5] = {16u, 23u, 31u, 43u, 59u};

    float enc[32];

    #pragma unroll
    for (int l = 0; l < 16; ++l) {
        const float sc = SC[l];
        // match numpy: mul then add (no FMA contraction; floor boundary safety)
        float p0 = __fadd_rn(__fmul_rn(x0, sc), 0.5f);
        float p1 = __fadd_rn(__fmul_rn(x1, sc), 0.5f);
        float p2 = __fadd_rn(__fmul_rn(x2, sc), 0.5f);
        float c0 = floorf(p0), c1 = floorf(p1), c2 = floorf(p2);
        float w0 = p0 - c0, w1 = p1 - c1, w2 = p2 - c2;
        // numpy f32->u32 cast of negatives wraps (via int64 trunc); |cell| < 2^31 here
        uint32_t ux = (uint32_t)(int)c0;
        uint32_t uy = (uint32_t)(int)c1;
        uint32_t uz = (uint32_t)(int)c2;

        uint32_t idx[8];
        if (l < 5) {
            const uint32_t r = RES[l], r2 = r * r;
            uint32_t ax0 = ux,      ax1 = ux + 1u;
            uint32_t ay0 = uy * r,  ay1 = ay0 + r;
            uint32_t az0 = uz * r2, az1 = az0 + r2;
            idx[0] = (ax0 + ay0 + az0) & TMASK;
            idx[1] = (ax1 + ay0 + az0) & TMASK;
            idx[2] = (ax0 + ay1 + az0) & TMASK;
            idx[3] = (ax1 + ay1 + az0) & TMASK;
            idx[4] = (ax0 + ay0 + az1) & TMASK;
            idx[5] = (ax1 + ay0 + az1) & TMASK;
            idx[6] = (ax0 + ay1 + az1) & TMASK;
            idx[7] = (ax1 + ay1 + az1) & TMASK;
        } else {
            uint32_t ax0 = ux,               ax1 = ux + 1u;
            uint32_t ay0 = uy * 2654435761u, ay1 = ay0 + 2654435761u;
            uint32_t az0 = uz * 805459861u,  az1 = az0 + 805459861u;
            idx[0] = (ax0 ^ ay0 ^ az0) & TMASK;
            idx[1] = (ax1 ^ ay0 ^ az0) & TMASK;
            idx[2] = (ax0 ^ ay1 ^ az0) & TMASK;
            idx[3] = (ax1 ^ ay1 ^ az0) & TMASK;
            idx[4] = (ax0 ^ ay0 ^ az1) & TMASK;
            idx[5] = (ax1 ^ ay0 ^ az1) & TMASK;
            idx[6] = (ax0 ^ ay1 ^ az1) & TMASK;
            idx[7] = (ax1 ^ ay1 ^ az1) & TMASK;
        }

        const F2* tl = (const F2*)tables + ((size_t)l << 19);
        F2 v[8];
        #pragma unroll
        for (int c = 0; c < 8; ++c) v[c] = tl[idx[c]];

        const float m0 = 1.0f - w0, m1 = 1.0f - w1, m2 = 1.0f - w2;
        float a0 = 0.0f, a1 = 0.0f;
        #pragma unroll
        for (int c = 0; c < 8; ++c) {
            const float wt = (((c & 1) ? w0 : m0) * ((c & 2) ? w1 : m1)) * ((c & 4) ? w2 : m2);
            a0 = fmaf(wt, v[c].x, a0);
            a1 = fmaf(wt, v[c].y, a1);
        }
        enc[2 * l]     = a0;
        enc[2 * l + 1] = a1;
    }

    // ---- MLP: weights indexed uniformly -> scalar (SGPR) loads ----
    float h1[64];
    #pragma unroll
    for (int j = 0; j < 64; ++j) h1[j] = b1[j];
    for (int i = 0; i < 32; ++i) {
        const float e = enc[i];
        #pragma unroll
        for (int j = 0; j < 64; ++j)
            h1[j] = fmaf(e, W1[i * 64 + j], h1[j]);
    }
    // softplus(100*z)/100, matching logaddexp(t, 0)
    #pragma unroll
    for (int j = 0; j < 64; ++j) {
        const float t = 100.0f * h1[j];
        const float m = fmaxf(t, 0.0f);
        h1[j] = (m + log1pf(expf(-fabsf(t)))) / 100.0f;
    }

    float h2[64];
    #pragma unroll
    for (int j = 0; j < 64; ++j) h2[j] = b2[j];
    for (int i = 0; i < 64; ++i) {
        const float e = h1[i];
        #pragma unroll
        for (int j = 0; j < 64; ++j)
            h2[j] = fmaf(e, W2[i * 64 + j], h2[j]);
    }

    float o[16];
    #pragma unroll
    for (int j = 0; j < 16; ++j) o[j] = b3[j];
    for (int i = 0; i < 64; ++i) {
        const float e = h2[i];
        #pragma unroll
        for (int j = 0; j < 16; ++j)
            o[j] = fmaf(e, W3[i * 16 + j], o[j]);
    }

    // Nontemporal output stream (don't evict tables from L2/L3).
    // Use native clang vector type: __builtin_nontemporal_store rejects
    // HIP's struct float4.
    v4f* op = (v4f*)(out + (size_t)gid * 16);
    v4f o0 = { o[0],  o[1],  o[2],  o[3]  };
    v4f o1 = { o[4],  o[5],  o[6],  o[7]  };
    v4f o2 = { o[8],  o[9],  o[10], o[11] };
    v4f o3 = { o[12], o[13], o[14], o[15] };
    __builtin_nontemporal_store(o0, op + 0);
    __builtin_nontemporal_store(o1, op + 1);
    __builtin_nontemporal_store(o2, op + 2);
    __builtin_nontemporal_store(o3, op + 3);
}

extern "C" void kernel_launch(void* const* d_in, const int* in_sizes, int n_in,
                              void* d_out, int out_size, void* d_ws, size_t ws_size,
                              hipStream_t stream) {
    const float* inp = (const float*)d_in[0];
    const float* tb  = (const float*)d_in[1];
    const float* W1  = (const float*)d_in[2];
    const float* b1  = (const float*)d_in[3];
    const float* W2  = (const float*)d_in[4];
    const float* b2  = (const float*)d_in[5];
    const float* W3  = (const float*)d_in[6];
    const float* b3  = (const float*)d_in[7];
    float* out = (float*)d_out;
    const int n = in_sizes[0] / 3;
    const int block = 256;
    const int grid = (n + block - 1) / block;
    hipLaunchKernelGGL(sdf_fused, dim3(grid), dim3(block), 0, stream,
                       inp, tb, W1, b1, W2, b2, W3, b3, out, n);
}

// Round 3
// 1862.680 us; speedup vs baseline: 1.0331x; 1.0331x over previous
//
#include <hip/hip_runtime.h>
#include <stdint.h>

#define TMASK ((1u << 19) - 1u)

typedef float v4f __attribute__((ext_vector_type(4)));

// ---- prep: convert fp32 tables -> packed bf16 (2 features = 1 uint32) ----
__global__ __launch_bounds__(256)
void cvt_tables(const float* __restrict__ tf, uint32_t* __restrict__ t16, int n_entries)
{
    int gid = blockIdx.x * blockDim.x + threadIdx.x;
    if (gid >= n_entries) return;
    const float fx = tf[2 * (size_t)gid + 0];
    const float fy = tf[2 * (size_t)gid + 1];
    uint32_t ax = __float_as_uint(fx);
    uint32_t ay = __float_as_uint(fy);
    // round-to-nearest-even bf16
    uint32_t rx = (ax + 0x7fffu + ((ax >> 16) & 1u)) >> 16;
    uint32_t ry = (ay + 0x7fffu + ((ay >> 16) & 1u)) >> 16;
    t16[gid] = rx | (ry << 16);
}

__global__ __launch_bounds__(256, 2)   // 256-VGPR budget: keep h1/h2 in VGPRs, no AGPR spill
void sdf_fused(const float* __restrict__ inp,
               const uint32_t* __restrict__ t16,
               const float* __restrict__ W1, const float* __restrict__ b1,
               const float* __restrict__ W2, const float* __restrict__ b2,
               const float* __restrict__ W3, const float* __restrict__ b3,
               float* __restrict__ out, int n)
{
    const int gid = blockIdx.x * blockDim.x + threadIdx.x;
    if (gid >= n) return;

    const float i0 = __builtin_nontemporal_load(inp + 3 * (size_t)gid + 0);
    const float i1 = __builtin_nontemporal_load(inp + 3 * (size_t)gid + 1);
    const float i2 = __builtin_nontemporal_load(inp + 3 * (size_t)gid + 2);
    const float x0 = (i0 + 3.0f) / 6.0f;
    const float x1 = (i1 + 3.0f) / 6.0f;
    const float x2 = (i2 + 3.0f) / 6.0f;

    constexpr float SC[16] = {
        15.0f,            21.1104f,         29.55436176f,     41.22307252259f,
        57.34806391006f,  79.63118951731f,  110.42424079360f, 152.97715835200f,
        211.78103512800f, 293.04211244300f, 405.33679518600f, 560.51681726700f,
        774.96008978200f, 1071.29924807000f,1480.81033091000f,2046.71369628000f };
    constexpr uint32_t RES[5] = {16u, 23u, 31u, 43u, 59u};

    float enc[32];

    #pragma unroll
    for (int l = 0; l < 16; ++l) {
        const float sc = SC[l];
        float p0 = __fadd_rn(__fmul_rn(x0, sc), 0.5f);
        float p1 = __fadd_rn(__fmul_rn(x1, sc), 0.5f);
        float p2 = __fadd_rn(__fmul_rn(x2, sc), 0.5f);
        float c0 = floorf(p0), c1 = floorf(p1), c2 = floorf(p2);
        float w0 = p0 - c0, w1 = p1 - c1, w2 = p2 - c2;
        uint32_t ux = (uint32_t)(int)c0;
        uint32_t uy = (uint32_t)(int)c1;
        uint32_t uz = (uint32_t)(int)c2;

        uint32_t idx[8];
        if (l < 5) {
            const uint32_t r = RES[l], r2 = r * r;
            uint32_t ax0 = ux,      ax1 = ux + 1u;
            uint32_t ay0 = uy * r,  ay1 = ay0 + r;
            uint32_t az0 = uz * r2, az1 = az0 + r2;
            idx[0] = (ax0 + ay0 + az0) & TMASK;
            idx[1] = (ax1 + ay0 + az0) & TMASK;
            idx[2] = (ax0 + ay1 + az0) & TMASK;
            idx[3] = (ax1 + ay1 + az0) & TMASK;
            idx[4] = (ax0 + ay0 + az1) & TMASK;
            idx[5] = (ax1 + ay0 + az1) & TMASK;
            idx[6] = (ax0 + ay1 + az1) & TMASK;
            idx[7] = (ax1 + ay1 + az1) & TMASK;
        } else {
            uint32_t ax0 = ux,               ax1 = ux + 1u;
            uint32_t ay0 = uy * 2654435761u, ay1 = ay0 + 2654435761u;
            uint32_t az0 = uz * 805459861u,  az1 = az0 + 805459861u;
            idx[0] = (ax0 ^ ay0 ^ az0) & TMASK;
            idx[1] = (ax1 ^ ay0 ^ az0) & TMASK;
            idx[2] = (ax0 ^ ay1 ^ az0) & TMASK;
            idx[3] = (ax1 ^ ay1 ^ az0) & TMASK;
            idx[4] = (ax0 ^ ay0 ^ az1) & TMASK;
            idx[5] = (ax1 ^ ay0 ^ az1) & TMASK;
            idx[6] = (ax0 ^ ay1 ^ az1) & TMASK;
            idx[7] = (ax1 ^ ay1 ^ az1) & TMASK;
        }

        const uint32_t* tl = t16 + ((size_t)l << 19);
        uint32_t v[8];
        #pragma unroll
        for (int c = 0; c < 8; ++c) v[c] = tl[idx[c]];

        const float m0 = 1.0f - w0, m1 = 1.0f - w1, m2 = 1.0f - w2;
        float a0 = 0.0f, a1 = 0.0f;
        #pragma unroll
        for (int c = 0; c < 8; ++c) {
            const float wt = (((c & 1) ? w0 : m0) * ((c & 2) ? w1 : m1)) * ((c & 4) ? w2 : m2);
            const float fx = __uint_as_float(v[c] << 16);
            const float fy = __uint_as_float(v[c] & 0xffff0000u);
            a0 = fmaf(wt, fx, a0);
            a1 = fmaf(wt, fy, a1);
        }
        enc[2 * l]     = a0;
        enc[2 * l + 1] = a1;
    }

    // ---- MLP: wave-uniform weight indices -> scalar loads + v_fmac ----
    float h1[64];
    #pragma unroll
    for (int j = 0; j < 64; ++j) h1[j] = b1[j];
    #pragma unroll
    for (int i = 0; i < 32; ++i) {
        const float e = enc[i];
        #pragma unroll
        for (int j = 0; j < 64; ++j)
            h1[j] = fmaf(e, W1[i * 64 + j], h1[j]);
    }
    #pragma unroll
    for (int j = 0; j < 64; ++j) {
        const float t = 100.0f * h1[j];
        const float m = fmaxf(t, 0.0f);
        h1[j] = (m + log1pf(expf(-fabsf(t)))) / 100.0f;
    }

    float h2[64];
    #pragma unroll
    for (int j = 0; j < 64; ++j) h2[j] = b2[j];
    #pragma unroll
    for (int i = 0; i < 64; ++i) {
        const float e = h1[i];
        #pragma unroll
        for (int j = 0; j < 64; ++j)
            h2[j] = fmaf(e, W2[i * 64 + j], h2[j]);
    }

    float o[16];
    #pragma unroll
    for (int j = 0; j < 16; ++j) o[j] = b3[j];
    #pragma unroll
    for (int i = 0; i < 64; ++i) {
        const float e = h2[i];
        #pragma unroll
        for (int j = 0; j < 16; ++j)
            o[j] = fmaf(e, W3[i * 16 + j], o[j]);
    }

    // Plain stores: wave writes 4KB contiguous, L2 write-combines to full lines.
    float4* op = (float4*)(out + (size_t)gid * 16);
    op[0] = make_float4(o[0],  o[1],  o[2],  o[3]);
    op[1] = make_float4(o[4],  o[5],  o[6],  o[7]);
    op[2] = make_float4(o[8],  o[9],  o[10], o[11]);
    op[3] = make_float4(o[12], o[13], o[14], o[15]);
}

extern "C" void kernel_launch(void* const* d_in, const int* in_sizes, int n_in,
                              void* d_out, int out_size, void* d_ws, size_t ws_size,
                              hipStream_t stream) {
    const float* inp = (const float*)d_in[0];
    const float* tb  = (const float*)d_in[1];
    const float* W1  = (const float*)d_in[2];
    const float* b1  = (const float*)d_in[3];
    const float* W2  = (const float*)d_in[4];
    const float* b2  = (const float*)d_in[5];
    const float* W3  = (const float*)d_in[6];
    const float* b3  = (const float*)d_in[7];
    float* out = (float*)d_out;

    uint32_t* t16 = (uint32_t*)d_ws;                 // 16*2^19 entries * 4B = 33.5 MB
    const int n_entries = in_sizes[1] / 2;           // L*T entries (F=2 floats each)
    hipLaunchKernelGGL(cvt_tables, dim3((n_entries + 255) / 256), dim3(256), 0, stream,
                       tb, t16, n_entries);

    const int n = in_sizes[0] / 3;
    hipLaunchKernelGGL(sdf_fused, dim3((n + 255) / 256), dim3(256), 0, stream,
                       inp, t16, W1, b1, W2, b2, W3, b3, out, n);
}

// Round 4
// 1296.146 us; speedup vs baseline: 1.4846x; 1.4371x over previous
//
#include <hip/hip_runtime.h>
#include <stdint.h>

#define TMASK ((1u << 19) - 1u)
#define CCENTER 0.0069314718055994530942f   // log(2)/100, same literal everywhere

typedef __bf16   v8bf __attribute__((ext_vector_type(8)));
typedef float    v4f  __attribute__((ext_vector_type(4)));
typedef uint32_t v4u  __attribute__((ext_vector_type(4)));

__device__ __host__ __forceinline__ uint32_t bf16_rne(float f) {
    uint32_t u = __float_as_uint(f);
    return (u + 0x7fffu + ((u >> 16) & 1u)) >> 16;
}

// ---- prep: fp32 tables -> packed bf16 pair per entry ----
__global__ __launch_bounds__(256)
void cvt_tables(const float* __restrict__ tf, uint32_t* __restrict__ t16, int n_entries)
{
    int gid = blockIdx.x * blockDim.x + threadIdx.x;
    if (gid >= n_entries) return;
    uint32_t rx = bf16_rne(tf[2 * (size_t)gid + 0]);
    uint32_t ry = bf16_rne(tf[2 * (size_t)gid + 1]);
    t16[gid] = rx | (ry << 16);
}

// ---- prep: weights -> MFMA B-fragment layout, bf16 hi/lo split ----
// frag ids: W1hi f0-3(nt), W1lo f4-7, W2hi f8-15(kc*4+nt), W2lo f16-23,
//           W3hi f24-25(kc), W3lo f26-27.  frag[f][lane][8 ushort]
__global__ __launch_bounds__(256)
void prep_frags(const float* __restrict__ W1, const float* __restrict__ W2,
                const float* __restrict__ W3, unsigned short* __restrict__ frag)
{
    int tid = blockIdx.x * blockDim.x + threadIdx.x;
    if (tid >= 28 * 64) return;
    int f = tid >> 6, lane = tid & 63;
    const float* W; int N, kc, nt, lo;
    if (f < 8)       { W = W1; N = 64; kc = 0; nt = f & 3; lo = (f >= 4); }
    else if (f < 24) { int g = f - 8;  W = W2; N = 64; lo = (g >= 8); g &= 7; kc = g >> 2; nt = g & 3; }
    else             { int g = f - 24; W = W3; N = 16; lo = (g >= 2); kc = g & 1; nt = 0; }
    int n  = nt * 16 + (lane & 15);
    int k0 = kc * 32 + (lane >> 4) * 8;
    unsigned short* dst = frag + ((size_t)f * 64 + lane) * 8;
    for (int j = 0; j < 8; ++j) {
        float w = W[(k0 + j) * N + n];
        uint32_t h = bf16_rne(w);
        if (lo) h = bf16_rne(w - __uint_as_float(h << 16));
        dst[j] = (unsigned short)h;
    }
}

// ---- prep: layer-2 centering correction: corr[j] = b2[j] + c * colsum(W2)[j]
__global__ void prep_corr(const float* __restrict__ W2, const float* __restrict__ b2,
                          float* __restrict__ corr)
{
    int j = threadIdx.x;   // 64 threads
    float s = 0.f;
    for (int i = 0; i < 64; ++i) s += W2[i * 64 + j];
    corr[j] = b2[j] + CCENTER * s;
}

#define MFMA16(A, B, C) __builtin_amdgcn_mfma_f32_16x16x32_bf16((A), (B), (C), 0, 0, 0)

__global__ __launch_bounds__(256, 4)
void sdf_fused(const float* __restrict__ inp,
               const uint32_t* __restrict__ t16,
               const v8bf* __restrict__ fr,          // weight B-frags
               const float* __restrict__ b1,
               const float* __restrict__ corr2,
               const float* __restrict__ b3,
               float* __restrict__ out, int n)
{
    const int gid  = blockIdx.x * 256 + threadIdx.x;
    const int wave = threadIdx.x >> 6;
    const int lane = threadIdx.x & 63;
    const int l15  = lane & 15;
    const int q    = lane >> 4;

    __shared__ unsigned short lds_s[4 * 4096];      // 8 KB per wave, reused enc->h1->h2
    unsigned short* wl = lds_s + wave * 4096;

    // ================= encode (unchanged from R3) =================
    const float i0 = __builtin_nontemporal_load(inp + 3 * (size_t)gid + 0);
    const float i1 = __builtin_nontemporal_load(inp + 3 * (size_t)gid + 1);
    const float i2 = __builtin_nontemporal_load(inp + 3 * (size_t)gid + 2);
    const float x0 = (i0 + 3.0f) / 6.0f;
    const float x1 = (i1 + 3.0f) / 6.0f;
    const float x2 = (i2 + 3.0f) / 6.0f;

    constexpr float SC[16] = {
        15.0f,            21.1104f,         29.55436176f,     41.22307252259f,
        57.34806391006f,  79.63118951731f,  110.42424079360f, 152.97715835200f,
        211.78103512800f, 293.04211244300f, 405.33679518600f, 560.51681726700f,
        774.96008978200f, 1071.29924807000f,1480.81033091000f,2046.71369628000f };
    constexpr uint32_t RES[5] = {16u, 23u, 31u, 43u, 59u};

    float enc[32];

    #pragma unroll
    for (int l = 0; l < 16; ++l) {
        const float sc = SC[l];
        float p0 = __fadd_rn(__fmul_rn(x0, sc), 0.5f);
        float p1 = __fadd_rn(__fmul_rn(x1, sc), 0.5f);
        float p2 = __fadd_rn(__fmul_rn(x2, sc), 0.5f);
        float c0 = floorf(p0), c1 = floorf(p1), c2 = floorf(p2);
        float w0 = p0 - c0, w1 = p1 - c1, w2 = p2 - c2;
        uint32_t ux = (uint32_t)(int)c0;
        uint32_t uy = (uint32_t)(int)c1;
        uint32_t uz = (uint32_t)(int)c2;

        uint32_t idx[8];
        if (l < 5) {
            const uint32_t r = RES[l], r2 = r * r;
            uint32_t ax0 = ux,      ax1 = ux + 1u;
            uint32_t ay0 = uy * r,  ay1 = ay0 + r;
            uint32_t az0 = uz * r2, az1 = az0 + r2;
            idx[0] = (ax0 + ay0 + az0) & TMASK;
            idx[1] = (ax1 + ay0 + az0) & TMASK;
            idx[2] = (ax0 + ay1 + az0) & TMASK;
            idx[3] = (ax1 + ay1 + az0) & TMASK;
            idx[4] = (ax0 + ay0 + az1) & TMASK;
            idx[5] = (ax1 + ay0 + az1) & TMASK;
            idx[6] = (ax0 + ay1 + az1) & TMASK;
            idx[7] = (ax1 + ay1 + az1) & TMASK;
        } else {
            uint32_t ax0 = ux,               ax1 = ux + 1u;
            uint32_t ay0 = uy * 2654435761u, ay1 = ay0 + 2654435761u;
            uint32_t az0 = uz * 805459861u,  az1 = az0 + 805459861u;
            idx[0] = (ax0 ^ ay0 ^ az0) & TMASK;
            idx[1] = (ax1 ^ ay0 ^ az0) & TMASK;
            idx[2] = (ax0 ^ ay1 ^ az0) & TMASK;
            idx[3] = (ax1 ^ ay1 ^ az0) & TMASK;
            idx[4] = (ax0 ^ ay0 ^ az1) & TMASK;
            idx[5] = (ax1 ^ ay0 ^ az1) & TMASK;
            idx[6] = (ax0 ^ ay1 ^ az1) & TMASK;
            idx[7] = (ax1 ^ ay1 ^ az1) & TMASK;
        }

        const uint32_t* tl = t16 + ((size_t)l << 19);
        uint32_t v[8];
        #pragma unroll
        for (int c = 0; c < 8; ++c) v[c] = tl[idx[c]];

        const float m0 = 1.0f - w0, m1 = 1.0f - w1, m2 = 1.0f - w2;
        float a0 = 0.0f, a1 = 0.0f;
        #pragma unroll
        for (int c = 0; c < 8; ++c) {
            const float wt = (((c & 1) ? w0 : m0) * ((c & 2) ? w1 : m1)) * ((c & 4) ? w2 : m2);
            a0 = fmaf(wt, __uint_as_float(v[c] << 16), a0);
            a1 = fmaf(wt, __uint_as_float(v[c] & 0xffff0000u), a1);
        }
        enc[2 * l]     = a0;
        enc[2 * l + 1] = a1;
    }

    // ============ enc -> LDS (bf16, row-major [pt][32], wave-private) ============
    {
        uint32_t w32[16];
        #pragma unroll
        for (int i = 0; i < 16; ++i)
            w32[i] = bf16_rne(enc[2 * i]) | (bf16_rne(enc[2 * i + 1]) << 16);
        v4u* dst = (v4u*)(wl + lane * 32);
        #pragma unroll
        for (int i = 0; i < 4; ++i)
            dst[i] = (v4u){w32[4 * i], w32[4 * i + 1], w32[4 * i + 2], w32[4 * i + 3]};
    }

    // ============ layer 1: [64x32] @ W1[32x64], softplus, center, -> LDS ============
    v8bf a1[4];
    #pragma unroll
    for (int mt = 0; mt < 4; ++mt)
        a1[mt] = *(const v8bf*)(wl + (mt * 16 + l15) * 32 + q * 8);

    #pragma unroll
    for (int nt = 0; nt < 4; ++nt) {
        v8bf bh = fr[(0 + nt) * 64 + lane];
        v8bf bl = fr[(4 + nt) * 64 + lane];
        float bias = b1[nt * 16 + l15];
        v4f cinit = {bias, bias, bias, bias};
        #pragma unroll
        for (int mt = 0; mt < 4; ++mt) {
            v4f acc = MFMA16(a1[mt], bh, cinit);
            acc     = MFMA16(a1[mt], bl, acc);
            #pragma unroll
            for (int r = 0; r < 4; ++r) {
                float t  = 100.0f * acc[r];
                float sp = (fmaxf(t, 0.0f) + log1pf(expf(-fabsf(t)))) / 100.0f;
                float hc = sp - CCENTER;   // centered: |hc| small -> bf16 quant error tiny
                wl[(mt * 16 + q * 4 + r) * 64 + nt * 16 + l15] = (unsigned short)bf16_rne(hc);
            }
        }
    }

    // ============ layer 2: h1c[64x64] @ W2[64x64] + (b2 + c*colsum W2) -> LDS ============
    v8bf a2[4][2];
    #pragma unroll
    for (int mt = 0; mt < 4; ++mt)
        #pragma unroll
        for (int kc = 0; kc < 2; ++kc)
            a2[mt][kc] = *(const v8bf*)(wl + (mt * 16 + l15) * 64 + kc * 32 + q * 8);

    #pragma unroll
    for (int nt = 0; nt < 4; ++nt) {
        v8bf b0h = fr[( 8 + nt) * 64 + lane];
        v8bf b1h = fr[(12 + nt) * 64 + lane];
        v8bf b0l = fr[(16 + nt) * 64 + lane];
        v8bf b1l = fr[(20 + nt) * 64 + lane];
        float cv = corr2[nt * 16 + l15];
        v4f cinit = {cv, cv, cv, cv};
        #pragma unroll
        for (int mt = 0; mt < 4; ++mt) {
            v4f acc = MFMA16(a2[mt][0], b0h, cinit);
            acc     = MFMA16(a2[mt][1], b1h, acc);
            acc     = MFMA16(a2[mt][0], b0l, acc);
            acc     = MFMA16(a2[mt][1], b1l, acc);
            #pragma unroll
            for (int r = 0; r < 4; ++r)
                wl[(mt * 16 + q * 4 + r) * 64 + nt * 16 + l15] = (unsigned short)bf16_rne(acc[r]);
        }
    }

    // ============ layer 3: h2[64x64] @ W3[64x16] + b3 -> global ============
    v8bf a3[4][2];
    #pragma unroll
    for (int mt = 0; mt < 4; ++mt)
        #pragma unroll
        for (int kc = 0; kc < 2; ++kc)
            a3[mt][kc] = *(const v8bf*)(wl + (mt * 16 + l15) * 64 + kc * 32 + q * 8);

    v8bf w3h0 = fr[24 * 64 + lane];
    v8bf w3h1 = fr[25 * 64 + lane];
    v8bf w3l0 = fr[26 * 64 + lane];
    v8bf w3l1 = fr[27 * 64 + lane];
    float cb = b3[l15];
    v4f cinit3 = {cb, cb, cb, cb};
    const int ptbase = blockIdx.x * 256 + wave * 64;
    #pragma unroll
    for (int mt = 0; mt < 4; ++mt) {
        v4f acc = MFMA16(a3[mt][0], w3h0, cinit3);
        acc     = MFMA16(a3[mt][1], w3h1, acc);
        acc     = MFMA16(a3[mt][0], w3l0, acc);
        acc     = MFMA16(a3[mt][1], w3l1, acc);
        #pragma unroll
        for (int r = 0; r < 4; ++r) {
            int pt = ptbase + mt * 16 + q * 4 + r;
            out[(size_t)pt * 16 + l15] = acc[r];
        }
    }
}

extern "C" void kernel_launch(void* const* d_in, const int* in_sizes, int n_in,
                              void* d_out, int out_size, void* d_ws, size_t ws_size,
                              hipStream_t stream) {
    const float* inp = (const float*)d_in[0];
    const float* tb  = (const float*)d_in[1];
    const float* W1  = (const float*)d_in[2];
    const float* b1  = (const float*)d_in[3];
    const float* W2  = (const float*)d_in[4];
    const float* b2  = (const float*)d_in[5];
    const float* W3  = (const float*)d_in[6];
    const float* b3  = (const float*)d_in[7];
    float* out = (float*)d_out;

    // ws layout: [0, 32MB) bf16 tables | +28672B weight frags | +256B corr2
    uint32_t*       t16  = (uint32_t*)d_ws;
    unsigned short* frag = (unsigned short*)((char*)d_ws + 33554432);
    float*          corr = (float*)((char*)d_ws + 33554432 + 28672);

    const int n_entries = in_sizes[1] / 2;   // L*T entries
    hipLaunchKernelGGL(cvt_tables, dim3((n_entries + 255) / 256), dim3(256), 0, stream,
                       tb, t16, n_entries);
    hipLaunchKernelGGL(prep_frags, dim3(7), dim3(256), 0, stream, W1, W2, W3, frag);
    hipLaunchKernelGGL(prep_corr, dim3(1), dim3(64), 0, stream, W2, b2, corr);

    const int n = in_sizes[0] / 3;           // 2^21: exact multiple of 256
    hipLaunchKernelGGL(sdf_fused, dim3(n / 256), dim3(256), 0, stream,
                       inp, t16, (const v8bf*)frag, b1, corr, b3, out, n);
}